// Round 14
// baseline (38.903 us; speedup 1.0000x reference)
//
#include <hip/hip_runtime.h>
#include <math.h>

#define NB 16
#define NL 64
#define NK 32
#define NC 32
#define ND 512
#define EPSF 1e-10f

#define TILES_PER_B 36
#define PAIR_BLOCKS (NB * TILES_PER_B * 2)   // 1152 half-tile blocks

// att iff jsd < 5  <=>  stat = H2_i + H2_j + 64 - S < 10/ln2
#define THRS 14.426950408889634f
#define L2E  1.4426950408889634f

typedef _Float16 half2v __attribute__((ext_vector_type(2)));
typedef _Float16 half4v __attribute__((ext_vector_type(4)));
typedef _Float16 half8v __attribute__((ext_vector_type(8)));

// ws layout (floats):
//   partials : PAIR_BLOCKS*4 at float offset 0
//   counter  : int at float offset 4608
//   P  (f16) : 1,048,576 halves (2 MB) at float offset 8192
//   H2 (f32x2): 1024 float2 after P
//   h16(f16) : 524,288 halves (1 MB) after H2

__global__ void __launch_bounds__(256) softmax_kernel(
        const float* __restrict__ prior,
        const float* __restrict__ hg,
        _Float16* __restrict__ P,
        float2* __restrict__ H2,
        _Float16* __restrict__ h16,
        int* __restrict__ counter) {
    int bl = blockIdx.x;
    int t  = threadIdx.x;
    if (bl == 0 && t == 0) *counter = 0;   // visible to next dispatch

    const float* src = prior + (size_t)bl * (NK * NC);
    float4 x = *(const float4*)(src + t * 4);
    float y0 = x.x * L2E, y1 = x.y * L2E, y2 = x.z * L2E, y3 = x.w * L2E;

    float m = fmaxf(fmaxf(y0, y1), fmaxf(y2, y3));
    #pragma unroll
    for (int w = 4; w >= 1; w >>= 1)
        m = fmaxf(m, __shfl_xor(m, w, 8));      // 8 lanes per k-row

    float e0 = exp2f(y0 - m), e1 = exp2f(y1 - m);
    float e2 = exp2f(y2 - m), e3 = exp2f(y3 - m);
    float s = e0 + e1 + e2 + e3;
    #pragma unroll
    for (int w = 4; w >= 1; w >>= 1)
        s += __shfl_xor(s, w, 8);

    float rs = 1.0f / s;
    float ls = __log2f(s);
    float p0 = e0 * rs, p1 = e1 * rs, p2 = e2 * rs, p3 = e3 * rs;
    float l0 = (y0 - m) - ls, l1 = (y1 - m) - ls;
    float l2 = (y2 - m) - ls, l3 = (y3 - m) - ls;

    half4v pv;
    pv[0] = (_Float16)fmaxf(p0, 1e-6f);
    pv[1] = (_Float16)fmaxf(p1, 1e-6f);
    pv[2] = (_Float16)fmaxf(p2, 1e-6f);
    pv[3] = (_Float16)fmaxf(p3, 1e-6f);
    *(half4v*)(P + (size_t)bl * (NK * NC) + t * 4) = pv;

    float2 hv = *(const float2*)(hg + (size_t)bl * ND + t * 2);
    half2v hh; hh[0] = (_Float16)hv.x; hh[1] = (_Float16)hv.y;
    *(half2v*)(h16 + (size_t)bl * ND + t * 2) = hh;

    float hacc = p0 * l0 + p1 * l1 + p2 * l2 + p3 * l3;
    #pragma unroll
    for (int w = 32; w >= 1; w >>= 1)
        hacc += __shfl_xor(hacc, w);
    __shared__ float red[4];
    int lane = t & 63, wib = t >> 6;
    if (lane == 0) red[wib] = hacc;      // wave w covers k in [8w, 8w+8)
    __syncthreads();
    if (t == 0)
        H2[bl] = make_float2(red[0] + red[1], red[2] + red[3]);
}

// 4-value butterfly: value q ends broadcast on lanes with (lane>>4)==q
__device__ __forceinline__ float bf4(float v0, float v1, float v2, float v3,
                                     bool hi32, bool hi16) {
    float sel0 = hi32 ? v2 : v0, oth0 = hi32 ? v0 : v2;
    float sel1 = hi32 ? v3 : v1, oth1 = hi32 ? v1 : v3;
    float w0 = sel0 + __shfl_xor(oth0, 32);
    float w1 = sel1 + __shfl_xor(oth1, 32);
    float sel = hi16 ? w1 : w0, oth = hi16 ? w0 : w1;
    float x = sel + __shfl_xor(oth, 16);
    x += __shfl_xor(x, 8);
    x += __shfl_xor(x, 4);
    x += __shfl_xor(x, 2);
    x += __shfl_xor(x, 1);
    return x;
}

// 1152 blocks x 256 threads (4 waves). R11 hot loop (i-row in registers,
// j-rows direct from L2-resident global, phase-B skip). Completion: atomic
// sc1 partial stores + release counter; last block acquires once and reduces.
__global__ void __launch_bounds__(256) pair_kernel(
        const _Float16* __restrict__ P,
        const float2* __restrict__ H2g,
        const _Float16* __restrict__ h16,
        float* __restrict__ partials,
        int* __restrict__ counter,
        float* __restrict__ out) {
    __shared__ float red[4][4];
    __shared__ int lastFlag;

    int tid  = threadIdx.x;
    int lane = tid & 63;
    int wv   = tid >> 6;

    int wg    = blockIdx.x;
    int b     = wg / (TILES_PER_B * 2);
    int rem72 = wg % (TILES_PER_B * 2);
    int t36   = rem72 >> 1;
    int half  = rem72 & 1;

    int ti = 0, rem = t36;
    while (rem >= 8 - ti) { rem -= 8 - ti; ++ti; }
    int tj = ti + rem;
    bool diag = (ti == tj);
    int bi0 = b * NL + ti * 8;
    int bj0 = b * NL + tj * 8;

    int r = half * 4 + wv;               // row within tile, 0..7

    // i-row straight from global into registers (read once, reused 8x)
    const _Float16* arow = P + (size_t)(bi0 + r) * (NK * NC);
    half8v ar1 = *(const half8v*)(arow + lane * 8);        // k < 16
    half8v ar2 = *(const half8v*)(arow + 512 + lane * 8);  // k >= 16
    half8v hr  = *(const half8v*)(h16 + (size_t)(bi0 + r) * ND + lane * 8);
    float2 h2i = H2g[bi0 + r];

    const _Float16* Pj = P   + (size_t)bj0 * (NK * NC);
    const _Float16* Hj = h16 + (size_t)bj0 * ND;

    bool hi32 = (lane & 32) != 0;
    bool hi16 = (lane & 16) != 0;
    int  sgrp = lane >> 4;               // 0..3

    float attN = 0.0f, attC = 0.0f, repN = 0.0f, repC = 0.0f;

    #pragma unroll
    for (int sb = 0; sb < 8; sb += 4) {
        float S[4], M[4];
        #pragma unroll
        for (int q = 0; q < 4; ++q) {
            int s = sb + q;
            half8v b1 = *(const half8v*)(Pj + s * 1024 + lane * 8);
            half8v t1 = ar1 + b1;
            float a0 = 0.f, a1 = 0.f;
            #pragma unroll
            for (int e = 0; e < 8; e += 2) {
                float f0 = (float)t1[e];     a0 = fmaf(f0, __log2f(f0), a0);
                float f1 = (float)t1[e + 1]; a1 = fmaf(f1, __log2f(f1), a1);
            }
            S[q] = a0 + a1;

            half8v hs = *(const half8v*)(Hj + s * 512 + lane * 8);
            half8v d = hr - hs;
            float m0 = 0.f, m1 = 0.f;
            #pragma unroll
            for (int e = 0; e < 8; e += 2) {
                m0 = fmaf((float)d[e],     (float)d[e],     m0);
                m1 = fmaf((float)d[e + 1], (float)d[e + 1], m1);
            }
            M[q] = m0 + m1;
        }

        float xSA = bf4(S[0], S[1], S[2], S[3], hi32, hi16);
        float xM  = bf4(M[0], M[1], M[2], M[3], hi32, hi16);

        int smine = sb + sgrp;
        float2 h2j = H2g[bj0 + smine];
        float statA = h2i.x + h2j.x + 32.0f - xSA;
        bool valid = (!diag) || (smine > r);
        float stat = statA;

        if (__any(valid && (statA < THRS))) {   // wave-uniform phase B
            float SB[4];
            #pragma unroll
            for (int q = 0; q < 4; ++q) {
                int s = sb + q;
                half8v b2 = *(const half8v*)(Pj + s * 1024 + 512 + lane * 8);
                half8v t2 = ar2 + b2;
                float a0 = 0.f, a1 = 0.f;
                #pragma unroll
                for (int e = 0; e < 8; e += 2) {
                    float g0 = (float)t2[e];     a0 = fmaf(g0, __log2f(g0), a0);
                    float g1 = (float)t2[e + 1]; a1 = fmaf(g1, __log2f(g1), a1);
                }
                SB[q] = a0 + a1;
            }
            float xSB = bf4(SB[0], SB[1], SB[2], SB[3], hi32, hi16);
            stat = statA + (h2i.y + h2j.y + 32.0f - xSB);
        }

        float mse   = xM * (1.0f / ND);
        float rterm = exp2f(-mse * L2E);
        bool act   = ((lane & 15) == 0) && valid;
        bool isAtt = stat < THRS;
        attN += (act && isAtt)  ? mse   : 0.0f;
        attC += (act && isAtt)  ? 1.0f  : 0.0f;
        repN += (act && !isAtt) ? rterm : 0.0f;
        repC += (act && !isAtt) ? 1.0f  : 0.0f;
    }

    // sum the 4 active lanes (0,16,32,48)
    attN += __shfl_xor(attN, 16); attN += __shfl_xor(attN, 32);
    attC += __shfl_xor(attC, 16); attC += __shfl_xor(attC, 32);
    repN += __shfl_xor(repN, 16); repN += __shfl_xor(repN, 32);
    repC += __shfl_xor(repC, 16); repC += __shfl_xor(repC, 32);

    if (lane == 0) {
        red[wv][0] = attN; red[wv][1] = attC;
        red[wv][2] = repN; red[wv][3] = repC;
    }
    __syncthreads();
    if (tid < 4) {
        float v = red[0][tid] + red[1][tid] + red[2][tid] + red[3][tid];
        __hip_atomic_store(&partials[blockIdx.x * 4 + tid], v,
                           __ATOMIC_RELAXED, __HIP_MEMORY_SCOPE_AGENT);
    }
    __syncthreads();   // drains vmcnt: the 4 sc1 stores are complete

    if (tid == 0) {
        int old = __hip_atomic_fetch_add(counter, 1, __ATOMIC_RELEASE,
                                         __HIP_MEMORY_SCOPE_AGENT);
        int last = (old == PAIR_BLOCKS - 1);
        if (last) {
            int c = __hip_atomic_load(counter, __ATOMIC_ACQUIRE,
                                      __HIP_MEMORY_SCOPE_AGENT);
            last = (c >= PAIR_BLOCKS);   // always true; keeps the acquire live
        }
        lastFlag = last;
    }
    __syncthreads();
    if (!lastFlag) return;

    // ---- last block: reduce all partials and write the two losses ----
    float a0 = 0.f, a1 = 0.f, a2 = 0.f, a3 = 0.f;
    for (int bkt = tid; bkt < PAIR_BLOCKS; bkt += 256) {
        a0 += __hip_atomic_load(&partials[bkt * 4 + 0], __ATOMIC_RELAXED, __HIP_MEMORY_SCOPE_AGENT);
        a1 += __hip_atomic_load(&partials[bkt * 4 + 1], __ATOMIC_RELAXED, __HIP_MEMORY_SCOPE_AGENT);
        a2 += __hip_atomic_load(&partials[bkt * 4 + 2], __ATOMIC_RELAXED, __HIP_MEMORY_SCOPE_AGENT);
        a3 += __hip_atomic_load(&partials[bkt * 4 + 3], __ATOMIC_RELAXED, __HIP_MEMORY_SCOPE_AGENT);
    }
    #pragma unroll
    for (int w = 32; w >= 1; w >>= 1) {
        a0 += __shfl_xor(a0, w);
        a1 += __shfl_xor(a1, w);
        a2 += __shfl_xor(a2, w);
        a3 += __shfl_xor(a3, w);
    }
    if (lane == 0) {
        red[wv][0] = a0; red[wv][1] = a1; red[wv][2] = a2; red[wv][3] = a3;
    }
    __syncthreads();
    if (tid == 0) {
        float s0 = red[0][0] + red[1][0] + red[2][0] + red[3][0];
        float s1 = red[0][1] + red[1][1] + red[2][1] + red[3][1];
        float s2 = red[0][2] + red[1][2] + red[2][2] + red[3][2];
        float s3 = red[0][3] + red[1][3] + red[2][3] + red[3][3];
        float la = s0 / (s1 + EPSF);
        float lr = s2 / (s3 + EPSF);
        out[0] = (la > 0.0f) ? la : 0.0f;
        out[1] = (lr > 0.0f) ? lr : 0.0f;
    }
}

extern "C" void kernel_launch(void* const* d_in, const int* in_sizes, int n_in,
                              void* d_out, int out_size, void* d_ws, size_t ws_size,
                              hipStream_t stream) {
    const float* prior = (const float*)d_in[0];
    const float* h     = (const float*)d_in[1];
    float* out = (float*)d_out;
    float* ws  = (float*)d_ws;

    float* partials = ws;                                    // 4608 floats
    int*   counter  = (int*)(ws + 4608);
    _Float16* P = (_Float16*)(ws + 8192);                    // 1,048,576 halves
    float2* H2 = (float2*)(ws + 8192 + 524288);              // 1024 float2
    _Float16* h16 = (_Float16*)(ws + 8192 + 524288 + 2048);  // 524,288 halves

    softmax_kernel<<<NB * NL, 256, 0, stream>>>(prior, h, P, H2, h16, counter);

    pair_kernel<<<PAIR_BLOCKS, 256, 0, stream>>>(P, H2, h16, partials, counter, out);
}

// Round 16
// 23.562 us; speedup vs baseline: 1.6511x; 1.6511x over previous
//
#include <hip/hip_runtime.h>
#include <math.h>

#define NB 16
#define NL 64
#define NK 32
#define NC 32
#define ND 512
#define EPSF 1e-10f

#define TILES_PER_B 36
#define PAIR_BLOCKS (NB * TILES_PER_B * 2)   // 1152 half-tile blocks

// att iff jsd < 5  <=>  stat = H2_i + H2_j + 64 - S < 10/ln2
#define THRS 14.426950408889634f
#define L2E  1.4426950408889634f

typedef _Float16 half2v __attribute__((ext_vector_type(2)));
typedef _Float16 half4v __attribute__((ext_vector_type(4)));
typedef _Float16 half8v __attribute__((ext_vector_type(8)));

// ws layout (floats):
//   partials : PAIR_BLOCKS*4 at float offset 0 (pad to 8192)
//   P  (f16) : 1,048,576 halves (2 MB) at float offset 8192
//   H2 (f32x2): 1024 float2 after P
//   h16(f16) : 524,288 halves (1 MB) after H2

__global__ void __launch_bounds__(256) softmax_kernel(
        const float* __restrict__ prior,
        const float* __restrict__ hg,
        _Float16* __restrict__ P,
        float2* __restrict__ H2,
        _Float16* __restrict__ h16) {
    int bl = blockIdx.x;
    int t  = threadIdx.x;

    const float* src = prior + (size_t)bl * (NK * NC);
    float4 x = *(const float4*)(src + t * 4);
    float y0 = x.x * L2E, y1 = x.y * L2E, y2 = x.z * L2E, y3 = x.w * L2E;

    float m = fmaxf(fmaxf(y0, y1), fmaxf(y2, y3));
    #pragma unroll
    for (int w = 4; w >= 1; w >>= 1)
        m = fmaxf(m, __shfl_xor(m, w, 8));      // 8 lanes per k-row

    float e0 = exp2f(y0 - m), e1 = exp2f(y1 - m);
    float e2 = exp2f(y2 - m), e3 = exp2f(y3 - m);
    float s = e0 + e1 + e2 + e3;
    #pragma unroll
    for (int w = 4; w >= 1; w >>= 1)
        s += __shfl_xor(s, w, 8);

    float rs = 1.0f / s;
    float ls = __log2f(s);
    float p0 = e0 * rs, p1 = e1 * rs, p2 = e2 * rs, p3 = e3 * rs;
    float l0 = (y0 - m) - ls, l1 = (y1 - m) - ls;
    float l2 = (y2 - m) - ls, l3 = (y3 - m) - ls;

    half4v pv;
    pv[0] = (_Float16)fmaxf(p0, 1e-6f);
    pv[1] = (_Float16)fmaxf(p1, 1e-6f);
    pv[2] = (_Float16)fmaxf(p2, 1e-6f);
    pv[3] = (_Float16)fmaxf(p3, 1e-6f);
    *(half4v*)(P + (size_t)bl * (NK * NC) + t * 4) = pv;

    float2 hv = *(const float2*)(hg + (size_t)bl * ND + t * 2);
    half2v hh; hh[0] = (_Float16)hv.x; hh[1] = (_Float16)hv.y;
    *(half2v*)(h16 + (size_t)bl * ND + t * 2) = hh;

    float hacc = p0 * l0 + p1 * l1 + p2 * l2 + p3 * l3;
    #pragma unroll
    for (int w = 32; w >= 1; w >>= 1)
        hacc += __shfl_xor(hacc, w);
    __shared__ float red[4];
    int lane = t & 63, wib = t >> 6;
    if (lane == 0) red[wib] = hacc;      // wave w covers k in [8w, 8w+8)
    __syncthreads();
    if (t == 0)
        H2[bl] = make_float2(red[0] + red[1], red[2] + red[3]);
}

// DPP funnel add: x += value of lane (i-N) within each 16-lane row
// (row_shr:N, bound_ctrl -> 0 past row start). Reduce-to-LAST-lane.
template<int CTRL>
__device__ __forceinline__ float dpp_add(float x) {
    int yi = __builtin_amdgcn_update_dpp(0, __float_as_int(x), CTRL, 0xF, 0xF, true);
    return x + __int_as_float(yi);
}

// 4-value reduce: value q's full sum lands on lane 16q+15 (last lane of
// row q). Order must be shr:1,2,4,8 (increasing). 2 ds ops + 4 DPP steps.
__device__ __forceinline__ float bf4f(float v0, float v1, float v2, float v3,
                                      bool hi32, bool hi16) {
    float sel0 = hi32 ? v2 : v0, oth0 = hi32 ? v0 : v2;
    float sel1 = hi32 ? v3 : v1, oth1 = hi32 ? v1 : v3;
    float w0 = sel0 + __shfl_xor(oth0, 32);
    float w1 = sel1 + __shfl_xor(oth1, 32);
    float sel = hi16 ? w1 : w0, oth = hi16 ? w0 : w1;
    float x = sel + __shfl_xor(oth, 16);
    x = dpp_add<0x111>(x);   // row_shr:1
    x = dpp_add<0x112>(x);   // row_shr:2
    x = dpp_add<0x114>(x);   // row_shr:4
    x = dpp_add<0x118>(x);   // row_shr:8
    return x;                // full sum valid on lanes with (lane&15)==15
}

// 1152 blocks x 256 threads (4 waves). R11 dataflow: i-row in registers,
// j-rows direct from L2-resident global. All 8 pairs' phase-A computed first,
// then 4 independent 2-deep-DS butterflies (DPP funnels). Phase B per batch
// of 4, wave-uniform skip. Sums valid on lanes 15,31,47,63.
__global__ void __launch_bounds__(256) pair_kernel(
        const _Float16* __restrict__ P,
        const float2* __restrict__ H2g,
        const _Float16* __restrict__ h16,
        float* __restrict__ partials) {
    __shared__ float red[4][4];

    int tid  = threadIdx.x;
    int lane = tid & 63;
    int wv   = tid >> 6;

    int wg    = blockIdx.x;
    int b     = wg / (TILES_PER_B * 2);
    int rem72 = wg % (TILES_PER_B * 2);
    int t36   = rem72 >> 1;
    int half  = rem72 & 1;

    int ti = 0, rem = t36;
    while (rem >= 8 - ti) { rem -= 8 - ti; ++ti; }
    int tj = ti + rem;
    bool diag = (ti == tj);
    int bi0 = b * NL + ti * 8;
    int bj0 = b * NL + tj * 8;

    int r = half * 4 + wv;               // row within tile, 0..7

    // i-row straight from global into registers (read once, reused 8x)
    const _Float16* arow = P + (size_t)(bi0 + r) * (NK * NC);
    half8v ar1 = *(const half8v*)(arow + lane * 8);        // k < 16
    half8v ar2 = *(const half8v*)(arow + 512 + lane * 8);  // k >= 16
    half8v hr  = *(const half8v*)(h16 + (size_t)(bi0 + r) * ND + lane * 8);
    float2 h2i = H2g[bi0 + r];

    const _Float16* Pj = P   + (size_t)bj0 * (NK * NC);
    const _Float16* Hj = h16 + (size_t)bj0 * ND;

    bool hi32 = (lane & 32) != 0;
    bool hi16 = (lane & 16) != 0;
    int  sgrp = lane >> 4;               // 0..3
    bool actl = (lane & 15) == 15;       // funnel target lanes

    // ---- phase A for all 8 pairs: S[s] (k<16) and M[s] ----
    float S[8], M[8];
    #pragma unroll
    for (int s = 0; s < 8; ++s) {
        half8v b1 = *(const half8v*)(Pj + s * 1024 + lane * 8);
        half8v t1 = ar1 + b1;
        float a0 = 0.f, a1 = 0.f;
        #pragma unroll
        for (int e = 0; e < 8; e += 2) {
            float f0 = (float)t1[e];     a0 = fmaf(f0, __log2f(f0), a0);
            float f1 = (float)t1[e + 1]; a1 = fmaf(f1, __log2f(f1), a1);
        }
        S[s] = a0 + a1;

        half8v hs = *(const half8v*)(Hj + s * 512 + lane * 8);
        half8v d = hr - hs;
        float m0 = 0.f, m1 = 0.f;
        #pragma unroll
        for (int e = 0; e < 8; e += 2) {
            m0 = fmaf((float)d[e],     (float)d[e],     m0);
            m1 = fmaf((float)d[e + 1], (float)d[e + 1], m1);
        }
        M[s] = m0 + m1;
    }

    // ---- 4 independent butterflies (2 ds each, chains interleave) ----
    float xSA0 = bf4f(S[0], S[1], S[2], S[3], hi32, hi16);
    float xSA1 = bf4f(S[4], S[5], S[6], S[7], hi32, hi16);
    float xM0  = bf4f(M[0], M[1], M[2], M[3], hi32, hi16);
    float xM1  = bf4f(M[4], M[5], M[6], M[7], hi32, hi16);

    int s0 = sgrp, s1 = 4 + sgrp;
    float2 h2j0 = H2g[bj0 + s0];
    float2 h2j1 = H2g[bj0 + s1];
    float statA0 = h2i.x + h2j0.x + 32.0f - xSA0;
    float statA1 = h2i.x + h2j1.x + 32.0f - xSA1;
    bool valid0 = (!diag) || (s0 > r);
    bool valid1 = (!diag) || (s1 > r);
    float stat0 = statA0, stat1 = statA1;

    // ---- phase B per batch, wave-uniform skip ----
    if (__any(actl && valid0 && (statA0 < THRS))) {
        float SB[4];
        #pragma unroll
        for (int q = 0; q < 4; ++q) {
            half8v b2 = *(const half8v*)(Pj + q * 1024 + 512 + lane * 8);
            half8v t2 = ar2 + b2;
            float a0 = 0.f, a1 = 0.f;
            #pragma unroll
            for (int e = 0; e < 8; e += 2) {
                float g0 = (float)t2[e];     a0 = fmaf(g0, __log2f(g0), a0);
                float g1 = (float)t2[e + 1]; a1 = fmaf(g1, __log2f(g1), a1);
            }
            SB[q] = a0 + a1;
        }
        float xSB = bf4f(SB[0], SB[1], SB[2], SB[3], hi32, hi16);
        stat0 = statA0 + (h2i.y + h2j0.y + 32.0f - xSB);
    }
    if (__any(actl && valid1 && (statA1 < THRS))) {
        float SB[4];
        #pragma unroll
        for (int q = 0; q < 4; ++q) {
            half8v b2 = *(const half8v*)(Pj + (q + 4) * 1024 + 512 + lane * 8);
            half8v t2 = ar2 + b2;
            float a0 = 0.f, a1 = 0.f;
            #pragma unroll
            for (int e = 0; e < 8; e += 2) {
                float g0 = (float)t2[e];     a0 = fmaf(g0, __log2f(g0), a0);
                float g1 = (float)t2[e + 1]; a1 = fmaf(g1, __log2f(g1), a1);
            }
            SB[q] = a0 + a1;
        }
        float xSB = bf4f(SB[0], SB[1], SB[2], SB[3], hi32, hi16);
        stat1 = statA1 + (h2i.y + h2j1.y + 32.0f - xSB);
    }

    // ---- classify both batches (act lanes hold true sums) ----
    float mse0 = xM0 * (1.0f / ND);
    float mse1 = xM1 * (1.0f / ND);
    float rt0  = exp2f(-mse0 * L2E);
    float rt1  = exp2f(-mse1 * L2E);
    bool att0 = stat0 < THRS;
    bool att1 = stat1 < THRS;

    float attN = 0.f, attC = 0.f, repN = 0.f, repC = 0.f;
    attN += (actl && valid0 && att0)  ? mse0 : 0.f;
    attC += (actl && valid0 && att0)  ? 1.f  : 0.f;
    repN += (actl && valid0 && !att0) ? rt0  : 0.f;
    repC += (actl && valid0 && !att0) ? 1.f  : 0.f;
    attN += (actl && valid1 && att1)  ? mse1 : 0.f;
    attC += (actl && valid1 && att1)  ? 1.f  : 0.f;
    repN += (actl && valid1 && !att1) ? rt1  : 0.f;
    repC += (actl && valid1 && !att1) ? 1.f  : 0.f;

    // sum the 4 active lanes (15,31,47,63)
    attN += __shfl_xor(attN, 16); attN += __shfl_xor(attN, 32);
    attC += __shfl_xor(attC, 16); attC += __shfl_xor(attC, 32);
    repN += __shfl_xor(repN, 16); repN += __shfl_xor(repN, 32);
    repC += __shfl_xor(repC, 16); repC += __shfl_xor(repC, 32);

    if (lane == 63) {
        red[wv][0] = attN; red[wv][1] = attC;
        red[wv][2] = repN; red[wv][3] = repC;
    }
    __syncthreads();
    if (tid < 4) {
        float v = red[0][tid] + red[1][tid] + red[2][tid] + red[3][tid];
        partials[blockIdx.x * 4 + tid] = v;
    }
}

__global__ void __launch_bounds__(256) finalize_kernel(
        const float* __restrict__ partials,
        float* __restrict__ out) {
    int tid = threadIdx.x;
    float a0 = 0.0f, a1 = 0.0f, a2 = 0.0f, a3 = 0.0f;
    for (int bkt = tid; bkt < PAIR_BLOCKS; bkt += 256) {
        a0 += partials[bkt * 4 + 0];
        a1 += partials[bkt * 4 + 1];
        a2 += partials[bkt * 4 + 2];
        a3 += partials[bkt * 4 + 3];
    }
    #pragma unroll
    for (int w = 32; w >= 1; w >>= 1) {
        a0 += __shfl_xor(a0, w);
        a1 += __shfl_xor(a1, w);
        a2 += __shfl_xor(a2, w);
        a3 += __shfl_xor(a3, w);
    }
    __shared__ float red[4][4];
    int lane = tid & 63, wib = tid >> 6;
    if (lane == 0) {
        red[wib][0] = a0; red[wib][1] = a1; red[wib][2] = a2; red[wib][3] = a3;
    }
    __syncthreads();
    if (tid == 0) {
        float s0 = red[0][0] + red[1][0] + red[2][0] + red[3][0];
        float s1 = red[0][1] + red[1][1] + red[2][1] + red[3][1];
        float s2 = red[0][2] + red[1][2] + red[2][2] + red[3][2];
        float s3 = red[0][3] + red[1][3] + red[2][3] + red[3][3];
        float la = s0 / (s1 + EPSF);
        float lr = s2 / (s3 + EPSF);
        out[0] = (la > 0.0f) ? la : 0.0f;
        out[1] = (lr > 0.0f) ? lr : 0.0f;
    }
}

extern "C" void kernel_launch(void* const* d_in, const int* in_sizes, int n_in,
                              void* d_out, int out_size, void* d_ws, size_t ws_size,
                              hipStream_t stream) {
    const float* prior = (const float*)d_in[0];
    const float* h     = (const float*)d_in[1];
    float* out = (float*)d_out;
    float* ws  = (float*)d_ws;

    float* partials = ws;                                    // 4608 floats
    _Float16* P = (_Float16*)(ws + 8192);                    // 1,048,576 halves
    float2* H2 = (float2*)(ws + 8192 + 524288);              // 1024 float2
    _Float16* h16 = (_Float16*)(ws + 8192 + 524288 + 2048);  // 524,288 halves

    softmax_kernel<<<NB * NL, 256, 0, stream>>>(prior, h, P, H2, h16);

    pair_kernel<<<PAIR_BLOCKS, 256, 0, stream>>>(P, H2, h16, partials);

    finalize_kernel<<<1, 256, 0, stream>>>(partials, out);
}